// Round 5
// baseline (346.765 us; speedup 1.0000x reference)
//
#include <hip/hip_runtime.h>

// B=4, P=12000, C=64, NX=NY=512
//   in[0]: pillar_embeddings float32 [B,P,C]
//   in[1]: pillar_coords     int32   [B,P,2]  (ix, iy)
//   in[2]: pillar_mask       int32   [B,P]
//   out:   float32 [B, C, NY, NX]
//
// Round-5: four different dense-write gathers (strided NT, reg-staged NT,
// sequential NT, sequential PLAIN) all ran our 256 MB write at ~2.5 TB/s
// (~110 us), while rocclr fillBufferAligned sustains 6.3 TB/s on the same
// buffer. Whatever the fill kernel does right, hipMemsetAsync gives it to
// us directly. So:
//   1) hipMemsetAsync(out, 0, 256 MB)  -> proven 6.3 TB/s path, ~43 us.
//   2) sparse scatter of ~24k valid pillars with PLAIN cached stores
//      (round-1's failure used NT 4B stores = per-store partial-line fabric
//      transactions; plain stores let L2 merge and write masked sectors).
//      One wave per pillar: coalesced 256 B emb-row read (1 dword/lane),
//      lane c stores out[b][c][iy][ix]. Wave-uniform mask exit. No map.
#define NXc 512
#define NYc 512
#define Bc  4
#define Pc  12000
#define Cc  64
#define CELLS (NXc * NYc)                 // 262144 cells per batch
#define OUT_BYTES ((size_t)Bc * Cc * CELLS * sizeof(float))   // 256 MB

__global__ void __launch_bounds__(256)
pillar_scatter_kernel(const float* __restrict__ emb,
                      const int* __restrict__ coords,
                      const int* __restrict__ mask,
                      float* __restrict__ out) {
    const int g    = blockIdx.x * 4 + (threadIdx.x >> 6);  // global pillar id
    const int lane = threadIdx.x & 63;                     // channel c

    // broadcast load (all lanes same address), wave-uniform branch
    if (mask[g] <= 0) return;

    const int ix   = coords[2 * g];       // broadcast
    const int iy   = coords[2 * g + 1];   // broadcast
    const int b    = g / Pc;
    const int cell = iy * NXc + ix;

    // coalesced: lanes read the 64 consecutive floats of this pillar's row
    const float v = emb[(size_t)g * Cc + lane];

    // plain cached store: lane c -> out[b][c][cell]; L2 merges the 4 B
    // partials and writes back masked sectors (~48 MB total HBM traffic).
    out[(size_t)(b * Cc + lane) * CELLS + cell] = v;
}

extern "C" void kernel_launch(void* const* d_in, const int* in_sizes, int n_in,
                              void* d_out, int out_size, void* d_ws, size_t ws_size,
                              hipStream_t stream) {
    const float* emb  = (const float*)d_in[0];
    const int* coords = (const int*)d_in[1];
    const int* mask   = (const int*)d_in[2];
    float* out        = (float*)d_out;

    // dense zero part: the rocclr fill path measured at 6.3 TB/s here
    hipMemsetAsync(out, 0, OUT_BYTES, stream);
    // sparse part: ~24k pillars, one wave each
    pillar_scatter_kernel<<<Bc * Pc / 4, 256, 0, stream>>>(emb, coords, mask, out);
}

// Round 6
// 343.346 us; speedup vs baseline: 1.0100x; 1.0100x over previous
//
#include <hip/hip_runtime.h>

// B=4, P=12000, C=64, NX=NY=512
//   in[0]: pillar_embeddings float32 [B,P,C]
//   in[1]: pillar_coords     int32   [B,P,2]  (ix, iy)
//   in[2]: pillar_mask       int32   [B,P]
//   out:   float32 [B, C, NY, NX]
//
// Round-6: component accounting across rounds 0-5 shows:
//   - pure store streams (memset/fill path) run ~6.3 TB/s (43 us / 256 MB)
//   - dense gathers (loads interleaved with a full 256 MB store stream)
//     cap at ~2.4 TB/s (~107 us) regardless of structure
//   - 4 B scattered stores cost ~82-142 us (transaction-rate wall)
// Hybrid: memset the output (fast pure-store path), then a dense sequential
// map sweep that stores ONLY the ~8.9% of float4 groups containing a valid
// cell (exec-masked). The interleaved store stream shrinks 256 MB -> ~48 MB
// of L2-merging partial lines; loads are L2-resident map + 12 MB emb.
#define NXc 512
#define NYc 512
#define Bc  4
#define Pc  12000
#define Cc  64
#define CELLS (NXc * NYc)            // 262144 cells per batch (2^18)
#define MAPN  (Bc * CELLS)           // 1,048,576 map entries (4 MB)
#define OUT_FV4 (Bc * Cc * (CELLS / 4))   // 16,777,216 float4 (256 MB)
#define PLANE4 (CELLS / 4)           // 65536 fv4 per c-plane
#define OUT_BYTES ((size_t)Bc * Cc * CELLS * sizeof(float))

typedef float fv4 __attribute__((ext_vector_type(4)));
typedef int   iv4 __attribute__((ext_vector_type(4)));

__global__ void map_scatter_kernel(const int* __restrict__ coords,
                                   const int* __restrict__ mask,
                                   int* __restrict__ map) {
    const int p = blockIdx.x * blockDim.x + threadIdx.x;   // global pillar id
    if (p >= Bc * Pc) return;
    if (mask[p] <= 0) return;
    const int ix = coords[2 * p];
    const int iy = coords[2 * p + 1];
    const int b = p / Pc;
    map[b * CELLS + iy * NXc + ix] = p;    // cells unique per batch -> no race
}

// One thread per output float4 (t = linear fv4 index, round-3 layout), but
// only threads whose 4-cell group contains a valid pillar perform loads and
// the store. 91% of threads read one L2-resident iv4 and exit.
__global__ void __launch_bounds__(256)
bev_sparse_gather_kernel(const float* __restrict__ emb,
                         const iv4* __restrict__ map4,
                         fv4* __restrict__ out4) {
    const int t     = blockIdx.x * blockDim.x + threadIdx.x;  // 0..OUT_FV4
    const int cell4 = t & (PLANE4 - 1);          // 0..65535
    const int plane = t >> 16;                   // b*64 + c
    const int c     = plane & (Cc - 1);
    const int b     = plane >> 6;

    // coalesced 16B/lane; map (4 MB/batch) is L2-resident
    const iv4 m = map4[(size_t)b * PLANE4 + cell4];

    // all four cells empty (sign bit of AND == AND of sign bits) -> done,
    // memset already wrote the zeros.
    if ((m.x & m.y & m.z & m.w) < 0) return;

    // clamped scalar gathers (empty sub-lanes read broadcast pillar-0 line)
    const float x0 = emb[(size_t)(m.x < 0 ? 0 : m.x) * Cc + c];
    const float x1 = emb[(size_t)(m.y < 0 ? 0 : m.y) * Cc + c];
    const float x2 = emb[(size_t)(m.z < 0 ? 0 : m.z) * Cc + c];
    const float x3 = emb[(size_t)(m.w < 0 ? 0 : m.w) * Cc + c];

    fv4 v;
    v.x = (m.x >= 0) ? x0 : 0.0f;
    v.y = (m.y >= 0) ? x1 : 0.0f;
    v.z = (m.z >= 0) ? x2 : 0.0f;
    v.w = (m.w >= 0) ? x3 : 0.0f;

    // plain cached store; merges over memset-resident lines in L2.
    out4[t] = v;
}

extern "C" void kernel_launch(void* const* d_in, const int* in_sizes, int n_in,
                              void* d_out, int out_size, void* d_ws, size_t ws_size,
                              hipStream_t stream) {
    const float* emb  = (const float*)d_in[0];
    const int* coords = (const int*)d_in[1];
    const int* mask   = (const int*)d_in[2];
    float* out        = (float*)d_out;
    int* map          = (int*)d_ws;          // 4 MB scratch

    hipMemsetAsync(out, 0, OUT_BYTES, stream);                      // dense zeros @ fill rate
    hipMemsetAsync(map, 0xFF, (size_t)MAPN * sizeof(int), stream);  // -1 fill
    map_scatter_kernel<<<(Bc * Pc + 255) / 256, 256, 0, stream>>>(coords, mask, map);
    bev_sparse_gather_kernel<<<OUT_FV4 / 256, 256, 0, stream>>>(emb, (const iv4*)map,
                                                                (fv4*)out);
}